// Round 1
// baseline (68.947 us; speedup 1.0000x reference)
//
#include <hip/hip_runtime.h>

#define GN 192
#define GNN (GN * GN)
#define GTOT (GN * GN * GN)   // 7,077,888 = 27,648 * 256
#define NSLOTS 256

// acc layout in d_ws: double acc[NSLOTS][2]  (mom, cont) = 4 KB

__global__ __launch_bounds__(256) void ns_loss_kernel(
    const float* __restrict__ u,      // (N,N,N,3)
    const float* __restrict__ uprev,  // (N,N,N,3)
    const float* __restrict__ p,      // (N,N,N)
    const float* __restrict__ rho,    // (N,N,N)
    const float* __restrict__ nu,     // (1,)
    const float* __restrict__ h,      // (3,)
    const float* __restrict__ dt,     // (1,)
    const float* __restrict__ grav,   // (3,)
    double* __restrict__ acc)
{
    const int idx = blockIdx.x * 256 + threadIdx.x;   // < GTOT exactly
    const int k = idx % GN;
    const int t = idx / GN;
    const int j = t % GN;
    const int i = t / GN;

    // uniform scalars (broadcast loads, cached)
    const float h0 = h[0], h1 = h[1], h2 = h[2];
    const float i2h0 = 0.5f / h0, i2h1 = 0.5f / h1, i2h2 = 0.5f / h2;
    const float ihs0 = 1.0f / (h0 * h0), ihs1 = 1.0f / (h1 * h1), ihs2 = 1.0f / (h2 * h2);
    const float invdt = 1.0f / dt[0];
    const float nu0 = nu[0];
    const float g0 = grav[0], g1 = grav[1], g2 = grav[2];

    // periodic neighbor cell indices
    const int kp = (k == GN - 1) ? idx - (GN - 1)       : idx + 1;
    const int km = (k == 0)      ? idx + (GN - 1)       : idx - 1;
    const int jp = (j == GN - 1) ? idx - (GN - 1) * GN  : idx + GN;
    const int jm = (j == 0)      ? idx + (GN - 1) * GN  : idx - GN;
    const int ip = (i == GN - 1) ? idx - (GN - 1) * GNN : idx + GNN;
    const int im = (i == 0)      ? idx + (GN - 1) * GNN : idx - GNN;

    // center + 6 neighbor velocity vectors
    const float* uc = u + 3 * idx;
    const float ucx = uc[0], ucy = uc[1], ucz = uc[2];

    const float* q;
    q = u + 3 * ip; const float xpx = q[0], xpy = q[1], xpz = q[2];
    q = u + 3 * im; const float xmx = q[0], xmy = q[1], xmz = q[2];
    q = u + 3 * jp; const float ypx = q[0], ypy = q[1], ypz = q[2];
    q = u + 3 * jm; const float ymx = q[0], ymy = q[1], ymz = q[2];
    q = u + 3 * kp; const float zpx = q[0], zpy = q[1], zpz = q[2];
    q = u + 3 * km; const float zmx = q[0], zmy = q[1], zmz = q[2];

    // central differences: dA.c = d u_c / d axisA
    const float dXx = (xpx - xmx) * i2h0, dXy = (xpy - xmy) * i2h0, dXz = (xpz - xmz) * i2h0;
    const float dYx = (ypx - ymx) * i2h1, dYy = (ypy - ymy) * i2h1, dYz = (ypz - ymz) * i2h1;
    const float dZx = (zpx - zmx) * i2h2, dZy = (zpy - zmy) * i2h2, dZz = (zpz - zmz) * i2h2;

    // laplacian of each component
    const float lapx = (xpx - 2.0f * ucx + xmx) * ihs0 + (ypx - 2.0f * ucx + ymx) * ihs1 + (zpx - 2.0f * ucx + zmx) * ihs2;
    const float lapy = (xpy - 2.0f * ucy + xmy) * ihs0 + (ypy - 2.0f * ucy + ymy) * ihs1 + (zpy - 2.0f * ucy + zmy) * ihs2;
    const float lapz = (xpz - 2.0f * ucz + xmz) * ihs0 + (ypz - 2.0f * ucz + ymz) * ihs1 + (zpz - 2.0f * ucz + zmz) * ihs2;

    // convection: conv.c = ux * dX.c + uy * dY.c + uz * dZ.c
    const float convx = ucx * dXx + ucy * dYx + ucz * dZx;
    const float convy = ucx * dXy + ucy * dYy + ucz * dZy;
    const float convz = ucx * dXz + ucy * dYz + ucz * dZz;

    // pressure gradient
    const float dpx = (p[ip] - p[im]) * i2h0;
    const float dpy = (p[jp] - p[jm]) * i2h1;
    const float dpz = (p[kp] - p[km]) * i2h2;

    const float inv_rho = 1.0f / (rho[idx] + 1e-8f);

    const float* upc = uprev + 3 * idx;
    const float dudtx = (ucx - upc[0]) * invdt;
    const float dudty = (ucy - upc[1]) * invdt;
    const float dudtz = (ucz - upc[2]) * invdt;

    const float Rx = dudtx + convx + dpx * inv_rho - nu0 * lapx - g0;
    const float Ry = dudty + convy + dpy * inv_rho - nu0 * lapy - g1;
    const float Rz = dudtz + convz + dpz * inv_rho - nu0 * lapz - g2;
    const float Rc = dXx + dYy + dZz;

    double mom = (double)Rx * Rx + (double)Ry * Ry + (double)Rz * Rz;
    double cont = (double)Rc * Rc;

    // wave(64) butterfly reduce
    #pragma unroll
    for (int off = 32; off > 0; off >>= 1) {
        mom  += __shfl_down(mom, off);
        cont += __shfl_down(cont, off);
    }

    __shared__ double smom[4], scont[4];
    const int wid = threadIdx.x >> 6;
    const int lane = threadIdx.x & 63;
    if (lane == 0) { smom[wid] = mom; scont[wid] = cont; }
    __syncthreads();
    if (threadIdx.x == 0) {
        const double m = smom[0] + smom[1] + smom[2] + smom[3];
        const double c = scont[0] + scont[1] + scont[2] + scont[3];
        double* slot = acc + 2 * (blockIdx.x & (NSLOTS - 1));
        unsafeAtomicAdd(slot, m);
        unsafeAtomicAdd(slot + 1, c);
    }
}

__global__ __launch_bounds__(256) void ns_finalize_kernel(const double* __restrict__ acc,
                                                          float* __restrict__ out)
{
    const int tid = threadIdx.x;
    double mom = acc[2 * tid];
    double cont = acc[2 * tid + 1];
    #pragma unroll
    for (int off = 32; off > 0; off >>= 1) {
        mom  += __shfl_down(mom, off);
        cont += __shfl_down(cont, off);
    }
    __shared__ double smom[4], scont[4];
    const int wid = tid >> 6;
    const int lane = tid & 63;
    if (lane == 0) { smom[wid] = mom; scont[wid] = cont; }
    __syncthreads();
    if (tid == 0) {
        const double m = (smom[0] + smom[1] + smom[2] + smom[3]) / (double)GTOT;
        const double c = (scont[0] + scont[1] + scont[2] + scont[3]) / (double)GTOT;
        out[0] = (float)(m + 10.0 * c);
        out[1] = (float)m;
        out[2] = (float)c;
    }
}

extern "C" void kernel_launch(void* const* d_in, const int* in_sizes, int n_in,
                              void* d_out, int out_size, void* d_ws, size_t ws_size,
                              hipStream_t stream)
{
    const float* u     = (const float*)d_in[0];
    const float* uprev = (const float*)d_in[1];
    const float* p     = (const float*)d_in[2];
    const float* rho   = (const float*)d_in[3];
    const float* nu    = (const float*)d_in[4];
    const float* h     = (const float*)d_in[5];
    const float* dt    = (const float*)d_in[6];
    const float* grav  = (const float*)d_in[7];

    double* acc = (double*)d_ws;

    hipMemsetAsync(d_ws, 0, NSLOTS * 2 * sizeof(double), stream);

    ns_loss_kernel<<<GTOT / 256, 256, 0, stream>>>(u, uprev, p, rho, nu, h, dt, grav, acc);
    ns_finalize_kernel<<<1, 256, 0, stream>>>(acc, (float*)d_out);
}